// Round 1
// baseline (418.430 us; speedup 1.0000x reference)
//
#include <hip/hip_runtime.h>
#include <hip/hip_bf16.h>

#define N_NODES 100000
#define NUM_TYPES 8
#define FACTOR 0.125f  // 1/sqrt(64)

__global__ __launch_bounds__(256) void edge_sum_kernel(
    const int* __restrict__ centers,
    const int* __restrict__ neighbors,
    const float* __restrict__ eng,
    const int* __restrict__ atom_type,
    const float* __restrict__ scales,
    float* __restrict__ out,
    int E)
{
    __shared__ float s_scales[NUM_TYPES * NUM_TYPES];
    if (threadIdx.x < NUM_TYPES * NUM_TYPES) {
        s_scales[threadIdx.x] = scales[threadIdx.x];
    }
    __syncthreads();

    const int n4 = E >> 2;  // E = 6.4M divisible by 4
    int tid = blockIdx.x * blockDim.x + threadIdx.x;
    int stride = gridDim.x * blockDim.x;

    for (int i = tid; i < n4; i += stride) {
        int4   c = ((const int4*)centers)[i];
        int4   n = ((const int4*)neighbors)[i];
        float4 e = ((const float4*)eng)[i];

        int sc0 = atom_type[c.x], sn0 = atom_type[n.x];
        int sc1 = atom_type[c.y], sn1 = atom_type[n.y];
        int sc2 = atom_type[c.z], sn2 = atom_type[n.z];
        int sc3 = atom_type[c.w], sn3 = atom_type[n.w];

        float v0 = e.x * s_scales[sc0 * NUM_TYPES + sn0] * FACTOR;
        float v1 = e.y * s_scales[sc1 * NUM_TYPES + sn1] * FACTOR;
        float v2 = e.z * s_scales[sc2 * NUM_TYPES + sn2] * FACTOR;
        float v3 = e.w * s_scales[sc3 * NUM_TYPES + sn3] * FACTOR;

        atomicAdd(&out[c.x], v0);
        atomicAdd(&out[c.y], v1);
        atomicAdd(&out[c.z], v2);
        atomicAdd(&out[c.w], v3);
    }

    // tail (E % 4), defensive — E = 6,400,000 is divisible by 4 so this is dead
    int tail_start = n4 << 2;
    for (int i = tail_start + tid; i < E; i += stride) {
        int c = centers[i];
        int n = neighbors[i];
        float v = eng[i] * s_scales[atom_type[c] * NUM_TYPES + atom_type[n]] * FACTOR;
        atomicAdd(&out[c], v);
    }
}

extern "C" void kernel_launch(void* const* d_in, const int* in_sizes, int n_in,
                              void* d_out, int out_size, void* d_ws, size_t ws_size,
                              hipStream_t stream) {
    const int E = in_sizes[1];  // edge_eng has E elements
    const int* edge_index = (const int*)d_in[0];   // [2, E]: centers then neighbors
    const float* edge_eng = (const float*)d_in[1]; // [E, 1]
    const int* atom_type = (const int*)d_in[2];    // [N, 1]
    const float* scales = (const float*)d_in[3];   // [T, T]
    float* out = (float*)d_out;

    const int* centers = edge_index;
    const int* neighbors = edge_index + E;

    // Harness poisons d_out with 0xAA before every timed launch — zero it.
    hipMemsetAsync(d_out, 0, (size_t)out_size * sizeof(float), stream);

    const int block = 256;
    const int n4 = E >> 2;
    int grid = (n4 + block - 1) / block;
    if (grid > 16384) grid = 16384;  // grid-stride caps launch size; 16384 blocks >> 256 CUs

    edge_sum_kernel<<<grid, block, 0, stream>>>(centers, neighbors, edge_eng,
                                                atom_type, scales, out, E);
}

// Round 2
// 403.574 us; speedup vs baseline: 1.0368x; 1.0368x over previous
//
#include <hip/hip_runtime.h>
#include <hip/hip_bf16.h>

#define N_NODES 100000
#define NUM_TYPES 8
#define FACTOR 0.125f  // 1/sqrt(64)

// Edge-scatter kernel: each thread handles 4 edges; atomics go to one of R
// replica accumulators (selected by blockIdx % R) to cut per-cacheline
// serialization at the device-scope atomic coherence point by ~R.
// unsafeAtomicAdd forces native global_atomic_add_f32 (no CAS loop).
__global__ __launch_bounds__(256) void edge_sum_kernel(
    const int* __restrict__ centers,
    const int* __restrict__ neighbors,
    const float* __restrict__ eng,
    const int* __restrict__ atom_type,
    const float* __restrict__ scales,
    float* __restrict__ partials,   // [R, N_NODES]
    int E, int R)
{
    __shared__ float s_scales[NUM_TYPES * NUM_TYPES];
    if (threadIdx.x < NUM_TYPES * NUM_TYPES) {
        s_scales[threadIdx.x] = scales[threadIdx.x];
    }
    __syncthreads();

    float* myout = partials + (size_t)(blockIdx.x % R) * N_NODES;

    const int n4 = E >> 2;
    int tid = blockIdx.x * blockDim.x + threadIdx.x;
    int stride = gridDim.x * blockDim.x;

    for (int i = tid; i < n4; i += stride) {
        int4   c = ((const int4*)centers)[i];
        int4   n = ((const int4*)neighbors)[i];
        float4 e = ((const float4*)eng)[i];

        int sc0 = atom_type[c.x], sn0 = atom_type[n.x];
        int sc1 = atom_type[c.y], sn1 = atom_type[n.y];
        int sc2 = atom_type[c.z], sn2 = atom_type[n.z];
        int sc3 = atom_type[c.w], sn3 = atom_type[n.w];

        float v0 = e.x * s_scales[sc0 * NUM_TYPES + sn0] * FACTOR;
        float v1 = e.y * s_scales[sc1 * NUM_TYPES + sn1] * FACTOR;
        float v2 = e.z * s_scales[sc2 * NUM_TYPES + sn2] * FACTOR;
        float v3 = e.w * s_scales[sc3 * NUM_TYPES + sn3] * FACTOR;

        unsafeAtomicAdd(&myout[c.x], v0);
        unsafeAtomicAdd(&myout[c.y], v1);
        unsafeAtomicAdd(&myout[c.z], v2);
        unsafeAtomicAdd(&myout[c.w], v3);
    }

    // tail (E % 4) — dead for E = 6,400,000, kept for safety
    int tail_start = n4 << 2;
    for (int i = tail_start + tid; i < E; i += stride) {
        int c = centers[i];
        int n = neighbors[i];
        float v = eng[i] * s_scales[atom_type[c] * NUM_TYPES + atom_type[n]] * FACTOR;
        unsafeAtomicAdd(&myout[c], v);
    }
}

// Sum R replicas into d_out.
__global__ __launch_bounds__(256) void reduce_kernel(
    const float* __restrict__ partials, float* __restrict__ out, int R)
{
    int i = blockIdx.x * blockDim.x + threadIdx.x;
    if (i < N_NODES) {
        float s = 0.0f;
        for (int r = 0; r < R; ++r) s += partials[(size_t)r * N_NODES + i];
        out[i] = s;
    }
}

extern "C" void kernel_launch(void* const* d_in, const int* in_sizes, int n_in,
                              void* d_out, int out_size, void* d_ws, size_t ws_size,
                              hipStream_t stream) {
    const int E = in_sizes[1];  // edge_eng element count
    const int* edge_index = (const int*)d_in[0];   // [2, E]
    const float* edge_eng = (const float*)d_in[1]; // [E, 1]
    const int* atom_type = (const int*)d_in[2];    // [N, 1]
    const float* scales = (const float*)d_in[3];   // [T, T]
    float* out = (float*)d_out;

    const int* centers = edge_index;
    const int* neighbors = edge_index + E;

    // Replica count bounded by workspace size.
    int R = (int)(ws_size / ((size_t)N_NODES * sizeof(float)));
    if (R > 8) R = 8;

    const int block = 256;
    const int n4 = E >> 2;
    int grid = (n4 + block - 1) / block;
    if (grid > 16384) grid = 16384;

    if (R >= 1) {
        float* partials = (float*)d_ws;
        hipMemsetAsync(partials, 0, (size_t)R * N_NODES * sizeof(float), stream);
        edge_sum_kernel<<<grid, block, 0, stream>>>(centers, neighbors, edge_eng,
                                                    atom_type, scales, partials, E, R);
        reduce_kernel<<<(N_NODES + block - 1) / block, block, 0, stream>>>(partials, out, R);
    } else {
        // Fallback: accumulate directly into out (R=1).
        hipMemsetAsync(d_out, 0, (size_t)out_size * sizeof(float), stream);
        edge_sum_kernel<<<grid, block, 0, stream>>>(centers, neighbors, edge_eng,
                                                    atom_type, scales, out, E, 1);
    }
}

// Round 3
// 206.549 us; speedup vs baseline: 2.0258x; 1.9539x over previous
//
#include <hip/hip_runtime.h>
#include <hip/hip_bf16.h>

#define N_NODES 100000
#define NUM_TYPES 8
#define FACTOR 0.125f  // 1/sqrt(64)

#define S_CHUNK 16128              // nodes per chunk; 16128*4B = 63 KB LDS bins
#define C_CHUNKS 7                 // ceil(100000 / 16128) = 7  (7*16128 = 112896)
#define B_MAX 73                   // segments per chunk -> grid = 7*73 = 511 blocks (~2/CU)

// Pass 1: block (c,b) scans edge-segment b; accumulates centers in chunk c into
// LDS bins via ds_add_f32 atomics; dumps bins to ws[(c*B+b)*S_CHUNK ..].
// No global atomics anywhere.
__global__ __launch_bounds__(512) void chunk_sum_kernel(
    const int* __restrict__ centers,
    const int* __restrict__ neighbors,
    const float* __restrict__ eng,
    const int* __restrict__ atom_type,
    const float* __restrict__ scales,
    float* __restrict__ ws,
    int E, int B)
{
    __shared__ float bins[S_CHUNK];
    __shared__ float s_scales[NUM_TYPES * NUM_TYPES];

    const int c = blockIdx.x / B;   // chunk index
    const int b = blockIdx.x % B;   // edge-segment index

    if (threadIdx.x < NUM_TYPES * NUM_TYPES) s_scales[threadIdx.x] = scales[threadIdx.x];
    for (int j = threadIdx.x; j < S_CHUNK; j += blockDim.x) bins[j] = 0.0f;
    __syncthreads();

    const int base = c * S_CHUNK;
    const int n4 = E >> 2;

    for (int i = b * blockDim.x + threadIdx.x; i < n4; i += B * blockDim.x) {
        int4   cc = ((const int4*)centers)[i];
        int4   nn = ((const int4*)neighbors)[i];
        float4 e  = ((const float4*)eng)[i];

        unsigned j0 = (unsigned)(cc.x - base);
        unsigned j1 = (unsigned)(cc.y - base);
        unsigned j2 = (unsigned)(cc.z - base);
        unsigned j3 = (unsigned)(cc.w - base);

        if (j0 < S_CHUNK)
            atomicAdd(&bins[j0], e.x * s_scales[atom_type[cc.x] * NUM_TYPES + atom_type[nn.x]] * FACTOR);
        if (j1 < S_CHUNK)
            atomicAdd(&bins[j1], e.y * s_scales[atom_type[cc.y] * NUM_TYPES + atom_type[nn.y]] * FACTOR);
        if (j2 < S_CHUNK)
            atomicAdd(&bins[j2], e.z * s_scales[atom_type[cc.z] * NUM_TYPES + atom_type[nn.z]] * FACTOR);
        if (j3 < S_CHUNK)
            atomicAdd(&bins[j3], e.w * s_scales[atom_type[cc.w] * NUM_TYPES + atom_type[nn.w]] * FACTOR);
    }

    // tail (E % 4) — dead for E = 6,400,000, handled by segment b==0 of each chunk
    if (b == 0) {
        for (int i = (n4 << 2) + (int)threadIdx.x; i < E; i += blockDim.x) {
            int cn = centers[i];
            unsigned j = (unsigned)(cn - base);
            if (j < S_CHUNK)
                atomicAdd(&bins[j], eng[i] * s_scales[atom_type[cn] * NUM_TYPES + atom_type[neighbors[i]]] * FACTOR);
        }
    }

    __syncthreads();
    float* dst = ws + ((size_t)c * B + b) * S_CHUNK;
    for (int j = threadIdx.x; j < S_CHUNK; j += blockDim.x) dst[j] = bins[j];
}

// Pass 2: out[n] = sum over B segment-partials of node n's chunk.
__global__ __launch_bounds__(256) void reduce_chunks_kernel(
    const float* __restrict__ ws, float* __restrict__ out, int B)
{
    int n = blockIdx.x * blockDim.x + threadIdx.x;
    if (n >= N_NODES) return;
    int c = n / S_CHUNK;
    int j = n - c * S_CHUNK;
    const float* p = ws + (size_t)c * B * S_CHUNK + j;
    float s = 0.0f;
    for (int b = 0; b < B; ++b) s += p[(size_t)b * S_CHUNK];
    out[n] = s;
}

// Fallback (tiny workspace only): direct atomic scatter into out.
__global__ __launch_bounds__(256) void edge_sum_atomic_kernel(
    const int* __restrict__ centers, const int* __restrict__ neighbors,
    const float* __restrict__ eng, const int* __restrict__ atom_type,
    const float* __restrict__ scales, float* __restrict__ out, int E)
{
    __shared__ float s_scales[NUM_TYPES * NUM_TYPES];
    if (threadIdx.x < NUM_TYPES * NUM_TYPES) s_scales[threadIdx.x] = scales[threadIdx.x];
    __syncthreads();
    int tid = blockIdx.x * blockDim.x + threadIdx.x;
    int stride = gridDim.x * blockDim.x;
    for (int i = tid; i < E; i += stride) {
        int cn = centers[i];
        float v = eng[i] * s_scales[atom_type[cn] * NUM_TYPES + atom_type[neighbors[i]]] * FACTOR;
        unsafeAtomicAdd(&out[cn], v);
    }
}

extern "C" void kernel_launch(void* const* d_in, const int* in_sizes, int n_in,
                              void* d_out, int out_size, void* d_ws, size_t ws_size,
                              hipStream_t stream) {
    const int E = in_sizes[1];  // edge_eng element count
    const int* edge_index = (const int*)d_in[0];   // [2, E]
    const float* edge_eng = (const float*)d_in[1]; // [E, 1]
    const int* atom_type = (const int*)d_in[2];    // [N, 1]
    const float* scales = (const float*)d_in[3];   // [T, T]
    float* out = (float*)d_out;

    const int* centers = edge_index;
    const int* neighbors = edge_index + E;

    // Workspace needed: C * B * S_CHUNK floats. Shrink B if ws is small.
    size_t per_b = (size_t)C_CHUNKS * S_CHUNK * sizeof(float);  // 451.6 KB per B
    int B = (int)(ws_size / per_b);
    if (B > B_MAX) B = B_MAX;

    if (B >= 1) {
        float* ws = (float*)d_ws;
        // No ws memset needed: every block writes its full bin array.
        chunk_sum_kernel<<<C_CHUNKS * B, 512, 0, stream>>>(
            centers, neighbors, edge_eng, atom_type, scales, ws, E, B);
        reduce_chunks_kernel<<<(N_NODES + 255) / 256, 256, 0, stream>>>(ws, out, B);
    } else {
        hipMemsetAsync(d_out, 0, (size_t)out_size * sizeof(float), stream);
        edge_sum_atomic_kernel<<<1024, 256, 0, stream>>>(
            centers, neighbors, edge_eng, atom_type, scales, out, E);
    }
}